// Round 3
// baseline (514.194 us; speedup 1.0000x reference)
//
#include <hip/hip_runtime.h>
#include <math.h>

#define NB   32     // batch
#define NH   32     // q heads
#define HKV  8      // kv heads
#define GQ   4      // q heads per kv head
#define DD   128    // head dim
#define BS   16     // page block size
#define MAXBLK 128  // pages per seq
#define LMAX 2048
#define CHUNK 256
#define NCHUNK (LMAX / CHUNK)   // 8

typedef float fx4 __attribute__((ext_vector_type(4)));  // nontemporal-compatible

// ---------------- Kernel 1: RoPE q (scaled) and new-k into workspace --------
__global__ __launch_bounds__(256) void rope_prep(
    const float* __restrict__ q, const float* __restrict__ k,
    const int* __restrict__ ctx, float* __restrict__ qrope,
    float* __restrict__ krope)
{
    int b = blockIdx.x;
    float pos = (float)ctx[b];
    const float QSCALE = 0.08838834764831845f;   // 128^-0.5
    for (int i = threadIdx.x; i < (NH + HKV) * DD; i += blockDim.x) {
        int row = i >> 7;
        int d   = i & (DD - 1);
        int j   = d & 63;
        // inv_freq = 10000^(-j/64) ; ln(10000)/64 = 0.14391156831212787
        float ang = pos * __expf(-(float)j * 0.14391156831212787f);
        float sv, cv;
        sincosf(ang, &sv, &cv);
        float sign = (d & 1) ? 1.0f : -1.0f;     // sign of neg_mask at (d^64)
        if (row < NH) {
            const float* src = q + ((size_t)b * NH + row) * DD;
            float v = src[d] * cv + sign * src[d ^ 64] * sv;
            qrope[((size_t)b * NH + row) * DD + d] = v * QSCALE;
        } else {
            int kvh = row - NH;
            const float* src = k + ((size_t)b * HKV + kvh) * DD;
            float v = src[d] * cv + sign * src[d ^ 64] * sv;
            krope[((size_t)b * HKV + kvh) * DD + d] = v;
        }
    }
}

// ---------------- Kernel 2: per-chunk flash-decoding partial ----------------
// grid: (chunk=8, kvh=8, b=32) = 2048 WGs, 256 threads (4 waves -> 8
// half-wave streams). Each half-wave (32 lanes x 16B = 512B) owns one token
// at a time, stride 8 over the chunk. K/V cache rows are read exactly once
// device-wide -> non-temporal loads (no L2/L3 reuse possible).
__global__ __launch_bounds__(256) void attn_partial(
    const float* __restrict__ kcache, const float* __restrict__ vcache,
    const float* __restrict__ qrope,  const float* __restrict__ krope,
    const float* __restrict__ vnew,   const int* __restrict__ btab,
    const int* __restrict__ ctx,      float* __restrict__ pacc,
    float* __restrict__ pml)
{
    int c   = blockIdx.x;
    int kvh = blockIdx.y;
    int b   = blockIdx.z;
    int L   = ctx[b];
    int start = c * CHUNK;
    if (start >= L) return;                     // inactive chunk (block-uniform)
    int end = min(start + CHUNK, L);

    __shared__ int   s_bt[CHUNK / BS];          // 16 page ids for this chunk
    __shared__ float s_q[GQ][DD];
    __shared__ float s_acc[8][GQ][DD];
    __shared__ float s_m[8];
    __shared__ float s_l[8][GQ];

    int tid = threadIdx.x;
    if (tid < CHUNK / BS)
        s_bt[tid] = btab[b * MAXBLK + c * (CHUNK / BS) + tid];
    for (int i = tid; i < GQ * DD; i += 256)
        ((float*)s_q)[i] = qrope[(size_t)(b * NH + kvh * GQ) * DD + i];
    __syncthreads();

    int w    = tid >> 6;
    int lane = tid & 63;
    int half = lane >> 5;
    int lq   = lane & 31;

    fx4 qf[GQ];
    #pragma unroll
    for (int g = 0; g < GQ; g++) qf[g] = *(const fx4*)&s_q[g][lq * 4];

    float m = -INFINITY;
    float lsum[GQ] = {0.f, 0.f, 0.f, 0.f};
    fx4   acc[GQ];
    #pragma unroll
    for (int g = 0; g < GQ; g++) acc[g] = (fx4)(0.f);

    const fx4* knew  = (const fx4*)&krope[(size_t)(b * HKV + kvh) * DD];
    const fx4* vnewr = (const fx4*)&vnew [(size_t)(b * HKV + kvh) * DD];

    int t = start + w * 2 + half;               // this stream's first token
    if (t < end) {
        // prologue load
        int blk = s_bt[(t - start) >> 4];
        size_t base = ((size_t)(blk * BS + (t & (BS - 1))) * HKV + kvh) * DD;
        bool nw = (t == L - 1);
        fx4 kf = nw ? knew[lq]
                    : __builtin_nontemporal_load(((const fx4*)&kcache[base]) + lq);
        fx4 vf = nw ? vnewr[lq]
                    : __builtin_nontemporal_load(((const fx4*)&vcache[base]) + lq);

        while (true) {
            // prefetch next token (one-deep pipeline)
            int tn = t + 8;
            fx4 kf2, vf2;
            if (tn < end) {
                int blk2 = s_bt[(tn - start) >> 4];
                size_t base2 = ((size_t)(blk2 * BS + (tn & (BS - 1))) * HKV + kvh) * DD;
                bool nw2 = (tn == L - 1);
                kf2 = nw2 ? knew[lq]
                          : __builtin_nontemporal_load(((const fx4*)&kcache[base2]) + lq);
                vf2 = nw2 ? vnewr[lq]
                          : __builtin_nontemporal_load(((const fx4*)&vcache[base2]) + lq);
            }
            // 4 GQA dots (partial over this lane's 4 d-values)
            float sg[GQ];
            #pragma unroll
            for (int g = 0; g < GQ; g++)
                sg[g] = qf[g].x * kf.x + qf[g].y * kf.y
                      + qf[g].z * kf.z + qf[g].w * kf.w;
            // butterfly reduce within the 32-lane half (xor 1..16)
            #pragma unroll
            for (int off = 1; off < 32; off <<= 1) {
                #pragma unroll
                for (int g = 0; g < GQ; g++)
                    sg[g] += __shfl_xor(sg[g], off, 64);
            }
            float smax = fmaxf(fmaxf(sg[0], sg[1]), fmaxf(sg[2], sg[3]));
            if (smax > m) {                      // rescale only when max grows
                float corr = __expf(m - smax);   // m=-inf first time -> 0
                #pragma unroll
                for (int g = 0; g < GQ; g++) {
                    lsum[g] *= corr;
                    acc[g] *= corr;
                }
                m = smax;
            }
            #pragma unroll
            for (int g = 0; g < GQ; g++) {
                float p = __expf(sg[g] - m);
                lsum[g] += p;
                acc[g] += p * vf;
            }
            if (tn >= end) break;
            t = tn; kf = kf2; vf = vf2;
        }
    }

    // ---- merge the 8 half-wave streams via LDS ----
    int stream = w * 2 + half;
    #pragma unroll
    for (int g = 0; g < GQ; g++)
        *(fx4*)&s_acc[stream][g][lq * 4] = acc[g];
    if (lq == 0) {
        s_m[stream] = m;
        #pragma unroll
        for (int g = 0; g < GQ; g++) s_l[stream][g] = lsum[g];
    }
    __syncthreads();

    float M = s_m[0];
    #pragma unroll
    for (int s = 1; s < 8; s++) M = fmaxf(M, s_m[s]);
    float f[8];
    #pragma unroll
    for (int s = 0; s < 8; s++) f[s] = __expf(s_m[s] - M);  // exp(-inf-M)=0

    size_t pbase = (size_t)(b * HKV + kvh) * NCHUNK + c;
    for (int idx = tid; idx < GQ * DD; idx += 256) {
        int g = idx >> 7;
        int d = idx & (DD - 1);
        float A = 0.f;
        #pragma unroll
        for (int s = 0; s < 8; s++) A += s_acc[s][g][d] * f[s];
        pacc[pbase * (GQ * DD) + idx] = A;
        if (d == 0) {
            float Lg = 0.f;
            #pragma unroll
            for (int s = 0; s < 8; s++) Lg += s_l[s][g] * f[s];
            pml[pbase * 8 + g] = Lg;
        }
    }
    if (tid == 0) pml[pbase * 8 + 4] = M;
}

// ---------------- Kernel 3: LSE-merge chunks, normalize, write out ----------
__global__ __launch_bounds__(256) void attn_reduce(
    const float* __restrict__ pacc, const float* __restrict__ pml,
    const int* __restrict__ ctx, float* __restrict__ out)
{
    int bk  = blockIdx.x;            // b*HKV + kvh
    int b   = bk >> 3;
    int kvh = bk & 7;
    int L   = ctx[b];
    int nc  = (L + CHUNK - 1) / CHUNK;
    const float* ml = &pml[(size_t)bk * NCHUNK * 8];

    float M = -INFINITY;
    for (int cc = 0; cc < nc; cc++) M = fmaxf(M, ml[cc * 8 + 4]);

    // hoist per-chunk rescale factors (uniform across threads)
    float fct[NCHUNK];
    for (int cc = 0; cc < nc; cc++) fct[cc] = __expf(ml[cc * 8 + 4] - M);

    for (int idx = threadIdx.x; idx < GQ * DD; idx += 256) {
        int g = idx >> 7;
        int d = idx & (DD - 1);
        float A = 0.f, Lg = 0.f;
        for (int cc = 0; cc < nc; cc++) {
            A  += pacc[((size_t)bk * NCHUNK + cc) * (GQ * DD) + idx] * fct[cc];
            Lg += ml[cc * 8 + g] * fct[cc];
        }
        out[((size_t)b * NH + kvh * GQ + g) * DD + d] = A / Lg;
    }
}

// ---------------------------------------------------------------------------
extern "C" void kernel_launch(void* const* d_in, const int* in_sizes, int n_in,
                              void* d_out, int out_size, void* d_ws, size_t ws_size,
                              hipStream_t stream)
{
    const float* q   = (const float*)d_in[0];
    const float* k   = (const float*)d_in[1];
    const float* v   = (const float*)d_in[2];
    const float* kc  = (const float*)d_in[3];
    const float* vc  = (const float*)d_in[4];
    const int*   bt  = (const int*)d_in[5];
    const int*   ctx = (const int*)d_in[6];
    float*       out = (float*)d_out;

    float* ws    = (float*)d_ws;
    float* qrope = ws;                                   // 32*32*128
    float* krope = qrope + (size_t)NB * NH * DD;         // 32*8*128
    float* pacc  = krope + (size_t)NB * HKV * DD;        // 2048*512
    float* pml   = pacc + (size_t)NB * HKV * NCHUNK * GQ * DD; // 2048*8
    // total ws: ~4.9 MB

    rope_prep<<<NB, 256, 0, stream>>>(q, k, ctx, qrope, krope);
    attn_partial<<<dim3(NCHUNK, HKV, NB), 256, 0, stream>>>(
        kc, vc, qrope, krope, v, bt, ctx, pacc, pml);
    attn_reduce<<<NB * HKV, 256, 0, stream>>>(pacc, pml, ctx, out);
}

// Round 5
// 490.696 us; speedup vs baseline: 1.0479x; 1.0479x over previous
//
#include <hip/hip_runtime.h>
#include <math.h>

#define NB   32     // batch
#define NH   32     // q heads
#define HKV  8      // kv heads
#define GQ   4      // q heads per kv head
#define DD   128    // head dim
#define BS   16     // page block size
#define MAXBLK 128  // pages per seq
#define LMAX 2048
#define CHUNK 256
#define NCHUNK (LMAX / CHUNK)   // 8

typedef float fx4 __attribute__((ext_vector_type(4)));  // nontemporal-compatible

// ---------------- Kernel 1: fused RoPE + per-chunk flash-decoding partial ---
// grid: (chunk=8, kvh=8, b=32) = 2048 WGs, 256 threads (4 waves -> 8
// half-wave streams). Each half-wave (32 lanes x 16B = 512B) owns one token
// at a time, stride 8 over the chunk. K/V cache rows are read exactly once
// device-wide -> non-temporal loads (no L2/L3 reuse possible).
// RoPE for this block's 4 q-rows + 1 new-k row is computed inline into LDS
// (640 elems / 256 threads, ~0.05us — removes the separate rope kernel).
__global__ __launch_bounds__(256) void attn_partial(
    const float* __restrict__ kcache, const float* __restrict__ vcache,
    const float* __restrict__ qin,    const float* __restrict__ kin,
    const float* __restrict__ vnew,   const int* __restrict__ btab,
    const int* __restrict__ ctx,      float* __restrict__ pacc,
    float* __restrict__ pml)
{
    int c   = blockIdx.x;
    int kvh = blockIdx.y;
    int b   = blockIdx.z;
    int L   = ctx[b];
    int start = c * CHUNK;
    if (start >= L) return;                     // inactive chunk (block-uniform)
    int end = min(start + CHUNK, L);

    __shared__ int   s_bt[CHUNK / BS];          // 16 page ids for this chunk
    __shared__ float s_q[GQ][DD];               // roped+scaled q (4 heads)
    __shared__ float s_k[DD];                   // roped new-k row
    __shared__ float s_acc[8][GQ][DD];
    __shared__ float s_m[8];
    __shared__ float s_l[8][GQ];

    int tid = threadIdx.x;
    if (tid < CHUNK / BS)
        s_bt[tid] = btab[b * MAXBLK + c * (CHUNK / BS) + tid];

    // ---- fused RoPE (positions = context_lens per the reference) ----
    {
        float pos = (float)L;
        const float QSCALE = 0.08838834764831845f;   // 128^-0.5
        for (int i = tid; i < (GQ + 1) * DD; i += 256) {
            int row = i >> 7;                    // 0..3 q rows, 4 = new-k
            int d   = i & (DD - 1);
            int j   = d & 63;
            // inv_freq = 10000^(-j/64); ln(10000)/64 = 0.14391156831212787
            float ang = pos * __expf(-(float)j * 0.14391156831212787f);
            float sv, cv;
            sincosf(ang, &sv, &cv);
            float sign = (d & 1) ? 1.0f : -1.0f; // neg_mask sign at (d^64)
            if (row < GQ) {
                const float* src = qin + ((size_t)(b * NH + kvh * GQ + row)) * DD;
                s_q[row][d] = (src[d] * cv + sign * src[d ^ 64] * sv) * QSCALE;
            } else {
                const float* src = kin + ((size_t)(b * HKV + kvh)) * DD;
                s_k[d] = src[d] * cv + sign * src[d ^ 64] * sv;
            }
        }
    }
    __syncthreads();

    int w    = tid >> 6;
    int lane = tid & 63;
    int half = lane >> 5;
    int lq   = lane & 31;
    int stream = w * 2 + half;

    fx4 qf[GQ];
    #pragma unroll
    for (int g = 0; g < GQ; g++) qf[g] = *(const fx4*)&s_q[g][lq * 4];

    float m = -INFINITY;
    float lsum[GQ] = {0.f, 0.f, 0.f, 0.f};
    fx4   acc[GQ];
    #pragma unroll
    for (int g = 0; g < GQ; g++) acc[g] = (fx4)(0.f);

    const fx4* vnewr = (const fx4*)&vnew[(size_t)(b * HKV + kvh) * DD];

    auto load_kv = [&](int t, fx4& kf, fx4& vf) {
        int blk = s_bt[(t - start) >> 4];
        size_t base = ((size_t)(blk * BS + (t & (BS - 1))) * HKV + kvh) * DD;
        if (t == L - 1) {                        // token being appended this step
            kf = *(const fx4*)&s_k[lq * 4];
            vf = vnewr[lq];
        } else {
            kf = __builtin_nontemporal_load(((const fx4*)&kcache[base]) + lq);
            vf = __builtin_nontemporal_load(((const fx4*)&vcache[base]) + lq);
        }
    };

    int t = start + stream;                      // this stream's first token
    if (t < end) {
        fx4 kfA, vfA, kfB, vfB;
        load_kv(t, kfA, vfA);                    // depth-0
        bool has1 = (t + 8) < end;
        if (has1) load_kv(t + 8, kfB, vfB);      // depth-1
        while (true) {
            int t2 = t + 16;
            bool has2 = t2 < end;
            fx4 kfC, vfC;
            if (has2) load_kv(t2, kfC, vfC);     // depth-2 prefetch
            // 4 GQA dots (partial over this lane's 4 d-values)
            float sg[GQ];
            #pragma unroll
            for (int g = 0; g < GQ; g++)
                sg[g] = qf[g].x * kfA.x + qf[g].y * kfA.y
                      + qf[g].z * kfA.z + qf[g].w * kfA.w;
            // butterfly reduce within the 32-lane half (xor 1..16)
            #pragma unroll
            for (int off = 1; off < 32; off <<= 1) {
                #pragma unroll
                for (int g = 0; g < GQ; g++)
                    sg[g] += __shfl_xor(sg[g], off, 64);
            }
            float smax = fmaxf(fmaxf(sg[0], sg[1]), fmaxf(sg[2], sg[3]));
            if (smax > m) {                      // rescale only when max grows
                float corr = __expf(m - smax);   // m=-inf first time -> 0
                #pragma unroll
                for (int g = 0; g < GQ; g++) {
                    lsum[g] *= corr;
                    acc[g] *= corr;
                }
                m = smax;
            }
            #pragma unroll
            for (int g = 0; g < GQ; g++) {
                float p = __expf(sg[g] - m);
                lsum[g] += p;
                acc[g] += p * vfA;
            }
            if (!has1) break;
            kfA = kfB; vfA = vfB; kfB = kfC; vfB = vfC;
            has1 = has2;
            t += 8;
        }
    }

    // ---- merge the 8 half-wave streams via LDS ----
    #pragma unroll
    for (int g = 0; g < GQ; g++)
        *(fx4*)&s_acc[stream][g][lq * 4] = acc[g];
    if (lq == 0) {
        s_m[stream] = m;
        #pragma unroll
        for (int g = 0; g < GQ; g++) s_l[stream][g] = lsum[g];
    }
    __syncthreads();

    float M = s_m[0];
    #pragma unroll
    for (int s = 1; s < 8; s++) M = fmaxf(M, s_m[s]);
    float f[8];
    #pragma unroll
    for (int s = 0; s < 8; s++) f[s] = __expf(s_m[s] - M);  // exp(-inf-M)=0

    size_t pbase = (size_t)(b * HKV + kvh) * NCHUNK + c;
    for (int idx = tid; idx < GQ * DD; idx += 256) {
        int g = idx >> 7;
        int d = idx & (DD - 1);
        float A = 0.f;
        #pragma unroll
        for (int s = 0; s < 8; s++) A += s_acc[s][g][d] * f[s];
        pacc[pbase * (GQ * DD) + idx] = A;
        if (d == 0) {
            float Lg = 0.f;
            #pragma unroll
            for (int s = 0; s < 8; s++) Lg += s_l[s][g] * f[s];
            pml[pbase * 8 + g] = Lg;
        }
    }
    if (tid == 0) pml[pbase * 8 + 4] = M;
}

// ---------------- Kernel 2: LSE-merge chunks, normalize, write out ----------
__global__ __launch_bounds__(256) void attn_reduce(
    const float* __restrict__ pacc, const float* __restrict__ pml,
    const int* __restrict__ ctx, float* __restrict__ out)
{
    int bk  = blockIdx.x;            // b*HKV + kvh
    int b   = bk >> 3;
    int kvh = bk & 7;
    int L   = ctx[b];
    int nc  = (L + CHUNK - 1) / CHUNK;
    const float* ml = &pml[(size_t)bk * NCHUNK * 8];

    float M = -INFINITY;
    for (int cc = 0; cc < nc; cc++) M = fmaxf(M, ml[cc * 8 + 4]);

    // hoist per-chunk rescale factors (uniform across threads)
    float fct[NCHUNK];
    for (int cc = 0; cc < nc; cc++) fct[cc] = __expf(ml[cc * 8 + 4] - M);

    for (int idx = threadIdx.x; idx < GQ * DD; idx += 256) {
        int g = idx >> 7;
        int d = idx & (DD - 1);
        float A = 0.f, Lg = 0.f;
        for (int cc = 0; cc < nc; cc++) {
            A  += pacc[((size_t)bk * NCHUNK + cc) * (GQ * DD) + idx] * fct[cc];
            Lg += ml[cc * 8 + g] * fct[cc];
        }
        out[((size_t)b * NH + kvh * GQ + g) * DD + d] = A / Lg;
    }
}

// ---------------------------------------------------------------------------
extern "C" void kernel_launch(void* const* d_in, const int* in_sizes, int n_in,
                              void* d_out, int out_size, void* d_ws, size_t ws_size,
                              hipStream_t stream)
{
    const float* q   = (const float*)d_in[0];
    const float* k   = (const float*)d_in[1];
    const float* v   = (const float*)d_in[2];
    const float* kc  = (const float*)d_in[3];
    const float* vc  = (const float*)d_in[4];
    const int*   bt  = (const int*)d_in[5];
    const int*   ctx = (const int*)d_in[6];
    float*       out = (float*)d_out;

    float* ws   = (float*)d_ws;
    float* pacc = ws;                                        // 2048*512 floats
    float* pml  = pacc + (size_t)NB * HKV * NCHUNK * GQ * DD; // 2048*8 floats
    // total ws: ~4.3 MB

    attn_partial<<<dim3(NCHUNK, HKV, NB), 256, 0, stream>>>(
        kc, vc, q, k, v, bt, ctx, pacc, pml);
    attn_reduce<<<NB * HKV, 256, 0, stream>>>(pacc, pml, ctx, out);
}